// Round 1
// baseline (2862.987 us; speedup 1.0000x reference)
//
#include <hip/hip_runtime.h>
#include <hip/hip_bf16.h>

#define B_ 2
#define C_ 256
#define NH_ 8
#define D_ 32
#define N_ 4096
#define SCALE_ 0.17677669529663689f

typedef __hip_bfloat16 bf16;

__device__ __forceinline__ float b2f(bf16 x) { return __bfloat162float(x); }
__device__ __forceinline__ bf16 f2b(float x) { return __float2bfloat16(x); }

// ---------------------------------------------------------------------------
// Kernel 1: QKV projection for BOTH sources (shared weights).
// qkv[((s*B_+b)*768 + o)*N_ + p], o: [0,256)=Q rows, [256,512)=K, [512,768)=V
// grid (N_/256, 768/16, 2*B_), block 256
// ---------------------------------------------------------------------------
__global__ __launch_bounds__(256)
void qkv_proj_kernel(const float* __restrict__ spatial,
                     const float* __restrict__ freq,
                     const float* __restrict__ wq, const float* __restrict__ bq,
                     const float* __restrict__ wk, const float* __restrict__ bk,
                     const float* __restrict__ wv, const float* __restrict__ bv,
                     bf16* __restrict__ qkv) {
  const int tid = threadIdx.x;
  const int p0 = blockIdx.x * 256;
  const int o0 = blockIdx.y * 16;
  const int z  = blockIdx.z;            // s*B_ + b
  const int s = z >> 1, b = z & 1;

  const float* x = (s == 0) ? spatial : freq;
  const float* w; const float* bias;
  int orow = o0;
  if (o0 < 256)      { w = wq; bias = bq; }
  else if (o0 < 512) { w = wk; bias = bk; orow = o0 - 256; }
  else               { w = wv; bias = bv; orow = o0 - 512; }

  __shared__ float xs[16][256];

  float acc[16];
  #pragma unroll
  for (int i = 0; i < 16; ++i) acc[i] = 0.f;

  for (int c0 = 0; c0 < C_; c0 += 16) {
    __syncthreads();
    #pragma unroll
    for (int i = 0; i < 16; ++i)
      xs[i][tid] = x[(size_t)(b * C_ + c0 + i) * N_ + p0 + tid];
    __syncthreads();
    #pragma unroll
    for (int kk = 0; kk < 16; ++kk) {
      float xv = xs[kk][tid];
      #pragma unroll
      for (int i = 0; i < 16; ++i)
        acc[i] += w[(orow + i) * C_ + c0 + kk] * xv;   // wave-uniform -> s_load
    }
  }

  bf16* dst = qkv + ((size_t)z * 768 + o0) * N_ + p0 + tid;
  #pragma unroll
  for (int i = 0; i < 16; ++i)
    dst[(size_t)i * N_] = f2b(acc[i] + bias[orow + i]);
}

// ---------------------------------------------------------------------------
// Kernel 2: flash attention. Direction s uses Q from source s, K/V from 1-s.
// atto[((s*B_+b)*C_ + c)*N_ + p], bf16.
// grid (N_/64, NH_, 2*B_), block 256 (4 waves)
// ---------------------------------------------------------------------------
__global__ __launch_bounds__(256)
void attn_kernel(const bf16* __restrict__ qkv, bf16* __restrict__ atto) {
  const int tid = threadIdx.x;
  const int m0 = blockIdx.x * 64;
  const int h  = blockIdx.y;
  const int z  = blockIdx.z;            // s*B_ + b
  const int s = z >> 1, b = z & 1;
  const int zo = ((1 - s) << 1) | b;    // kv source

  const bf16* Q = qkv + ((size_t)z  * 768 +   0 + h * D_) * N_;
  const bf16* K = qkv + ((size_t)zo * 768 + 256 + h * D_) * N_;
  const bf16* V = qkv + ((size_t)zo * 768 + 512 + h * D_) * N_;

  __shared__ float qs[D_][64];
  __shared__ float ks[D_][64];
  __shared__ float vs[D_][64];
  __shared__ float sc[64][65];          // stride 65 -> conflict-free columns
  __shared__ float mi[64], li[64], al[64];

  // stage Q (pre-scaled)
  #pragma unroll
  for (int j = 0; j < 8; ++j) {
    int idx = tid + 256 * j;            // 0..2047
    int d = idx >> 6, mm = idx & 63;
    qs[d][mm] = SCALE_ * b2f(Q[(size_t)d * N_ + m0 + mm]);
  }
  if (tid < 64) { mi[tid] = -1e30f; li[tid] = 0.f; }
  __syncthreads();

  const int m   = tid & 63;
  const int grp = tid >> 6;             // 0..3

  float qreg[D_];
  #pragma unroll
  for (int d = 0; d < D_; ++d) qreg[d] = qs[d][m];

  float om[8];
  #pragma unroll
  for (int j = 0; j < 8; ++j) om[j] = 0.f;

  for (int n0 = 0; n0 < N_; n0 += 64) {
    __syncthreads();                    // protect ks/vs/sc from previous iter
    #pragma unroll
    for (int j = 0; j < 8; ++j) {
      int idx = tid + 256 * j;
      int d = idx >> 6, n = idx & 63;
      ks[d][n] = b2f(K[(size_t)d * N_ + n0 + n]);
      vs[d][n] = b2f(V[(size_t)d * N_ + n0 + n]);
    }
    __syncthreads();

    // scores: thread -> row m, cols grp*16..grp*16+15
    #pragma unroll
    for (int i = 0; i < 16; ++i) {
      int n = grp * 16 + i;
      float a = 0.f;
      #pragma unroll
      for (int d = 0; d < D_; ++d) a += qreg[d] * ks[d][n];
      sc[m][n] = a;
    }
    __syncthreads();

    // online softmax (wave 0 handles one row per lane)
    if (tid < 64) {
      float rm = mi[tid];
      #pragma unroll 8
      for (int n = 0; n < 64; ++n) rm = fmaxf(rm, sc[tid][n]);
      float a = __expf(mi[tid] - rm);
      float sum = 0.f;
      #pragma unroll 8
      for (int n = 0; n < 64; ++n) {
        float p = __expf(sc[tid][n] - rm);
        sc[tid][n] = p;
        sum += p;
      }
      li[tid] = li[tid] * a + sum;
      mi[tid] = rm;
      al[tid] = a;
    }
    __syncthreads();

    // PV: wave grp handles d rows [8*grp, 8*grp+8)
    float a = al[m];
    #pragma unroll
    for (int j = 0; j < 8; ++j) om[j] *= a;
    for (int n = 0; n < 64; ++n) {
      float p = sc[m][n];
      #pragma unroll
      for (int j = 0; j < 8; ++j)
        om[j] += vs[grp * 8 + j][n] * p;
    }
  }

  float inv = 1.f / li[m];
  bf16* O = atto + ((size_t)z * C_ + h * D_) * N_ + m0 + m;
  #pragma unroll
  for (int j = 0; j < 8; ++j)
    O[(size_t)(grp * 8 + j) * N_] = f2b(om[j] * inv);
}

// ---------------------------------------------------------------------------
// Kernel 3: out = spatial + freq + Wo*(attS + attF) + 2*bo
// grid (N_/256, C_/16, B_), block 256
// ---------------------------------------------------------------------------
__global__ __launch_bounds__(256)
void out_proj_kernel(const bf16* __restrict__ atto,
                     const float* __restrict__ spatial,
                     const float* __restrict__ freq,
                     const float* __restrict__ wo, const float* __restrict__ bo,
                     float* __restrict__ out) {
  const int tid = threadIdx.x;
  const int p0 = blockIdx.x * 256;
  const int o0 = blockIdx.y * 16;
  const int b  = blockIdx.z;

  const bf16* a0 = atto + ((size_t)(0 * B_ + b) * C_) * N_;
  const bf16* a1 = atto + ((size_t)(1 * B_ + b) * C_) * N_;

  __shared__ float xs[16][256];
  float acc[16];
  #pragma unroll
  for (int i = 0; i < 16; ++i) acc[i] = 0.f;

  for (int c0 = 0; c0 < C_; c0 += 16) {
    __syncthreads();
    #pragma unroll
    for (int i = 0; i < 16; ++i) {
      size_t off = (size_t)(c0 + i) * N_ + p0 + tid;
      xs[i][tid] = b2f(a0[off]) + b2f(a1[off]);
    }
    __syncthreads();
    #pragma unroll
    for (int kk = 0; kk < 16; ++kk) {
      float xv = xs[kk][tid];
      #pragma unroll
      for (int i = 0; i < 16; ++i)
        acc[i] += wo[(o0 + i) * C_ + c0 + kk] * xv;
    }
  }

  #pragma unroll
  for (int i = 0; i < 16; ++i) {
    size_t off = (size_t)(b * C_ + o0 + i) * N_ + p0 + tid;
    out[off] = acc[i] + 2.f * bo[o0 + i] + spatial[off] + freq[off];
  }
}

extern "C" void kernel_launch(void* const* d_in, const int* in_sizes, int n_in,
                              void* d_out, int out_size, void* d_ws, size_t ws_size,
                              hipStream_t stream) {
  const float* spatial = (const float*)d_in[0];
  const float* freq    = (const float*)d_in[1];
  const float* wq = (const float*)d_in[2];
  const float* bq = (const float*)d_in[3];
  const float* wk = (const float*)d_in[4];
  const float* bk = (const float*)d_in[5];
  const float* wv = (const float*)d_in[6];
  const float* bv = (const float*)d_in[7];
  const float* wo = (const float*)d_in[8];
  const float* bo = (const float*)d_in[9];
  float* out = (float*)d_out;

  // workspace: qkv (2 srcs x B x 768 x N, bf16) = 50.3 MB, atto = 16.8 MB
  bf16* qkv  = (bf16*)d_ws;
  bf16* atto = (bf16*)((char*)d_ws + (size_t)2 * B_ * 768 * N_ * sizeof(bf16));

  qkv_proj_kernel<<<dim3(N_ / 256, 768 / 16, 2 * B_), 256, 0, stream>>>(
      spatial, freq, wq, bq, wk, bk, wv, bv, qkv);
  attn_kernel<<<dim3(N_ / 64, NH_, 2 * B_), 256, 0, stream>>>(qkv, atto);
  out_proj_kernel<<<dim3(N_ / 256, C_ / 16, B_), 256, 0, stream>>>(
      atto, spatial, freq, wo, bo, out);
}

// Round 2
// 591.971 us; speedup vs baseline: 4.8364x; 4.8364x over previous
//
#include <hip/hip_runtime.h>
#include <hip/hip_bf16.h>

#define B_ 2
#define C_ 256
#define NH_ 8
#define D_ 32
#define N_ 4096
#define SCALE_ 0.17677669529663689f

typedef __hip_bfloat16 bf16;
typedef __attribute__((ext_vector_type(8))) short sx8;   // 8 bf16 = one MFMA A/B frag
typedef __attribute__((ext_vector_type(4))) short sx4;
typedef __attribute__((ext_vector_type(4))) float fx4;   // MFMA C/D frag

__device__ __forceinline__ float b2f(bf16 x) { return __bfloat162float(x); }
__device__ __forceinline__ bf16 f2b(float x) { return __float2bfloat16(x); }
__device__ __forceinline__ short fbs(float x) { bf16 h = __float2bfloat16(x); return *(short*)&h; }
// wave-local LDS ordering for the P round-trip (cross-lane through LDS is
// invisible to compiler alias analysis — must fence explicitly)
__device__ __forceinline__ void lds_fence() { asm volatile("s_waitcnt lgkmcnt(0)" ::: "memory"); }

// ---------------------------------------------------------------------------
// Kernel 1: QKV projection, shared weights, both sources.
// Q,K written POS-MAJOR:  qt/kt[z][p][c]   (c contiguous -> MFMA frag = 16B load)
// V written d-major:      v[z][c][p]       (PV A-operand wants natural (d,n))
// grid (N_/256, 768/16, 2*B_), block 256
// ---------------------------------------------------------------------------
__global__ __launch_bounds__(256)
void qkv_proj_kernel(const float* __restrict__ spatial,
                     const float* __restrict__ freq,
                     const float* __restrict__ wq, const float* __restrict__ bq,
                     const float* __restrict__ wk, const float* __restrict__ bk,
                     const float* __restrict__ wv, const float* __restrict__ bv,
                     bf16* __restrict__ qt, bf16* __restrict__ kt,
                     bf16* __restrict__ v) {
  const int tid = threadIdx.x;
  const int p0 = blockIdx.x * 256;
  const int o0 = blockIdx.y * 16;
  const int z  = blockIdx.z;            // s*B_ + b
  const int s = z >> 1, b = z & 1;

  const float* x = (s == 0) ? spatial : freq;
  const float* w; const float* bias;
  int orow = o0;
  if (o0 < 256)      { w = wq; bias = bq; }
  else if (o0 < 512) { w = wk; bias = bk; orow = o0 - 256; }
  else               { w = wv; bias = bv; orow = o0 - 512; }

  __shared__ float xs[16][256];

  float acc[16];
  #pragma unroll
  for (int i = 0; i < 16; ++i) acc[i] = 0.f;

  for (int c0 = 0; c0 < C_; c0 += 16) {
    __syncthreads();
    #pragma unroll
    for (int i = 0; i < 16; ++i)
      xs[i][tid] = x[(size_t)(b * C_ + c0 + i) * N_ + p0 + tid];
    __syncthreads();
    #pragma unroll
    for (int kk = 0; kk < 16; ++kk) {
      float xv = xs[kk][tid];
      #pragma unroll
      for (int i = 0; i < 16; ++i)
        acc[i] += w[(orow + i) * C_ + c0 + kk] * xv;   // wave-uniform -> s_load
    }
  }

  if (o0 < 512) {
    bf16* base = ((o0 < 256) ? qt : kt) +
                 ((size_t)z * N_ + p0 + tid) * C_ + orow;
    short tmp[16];
    #pragma unroll
    for (int i = 0; i < 16; ++i) tmp[i] = fbs(acc[i] + bias[orow + i]);
    *(sx8*)base       = *(sx8*)&tmp[0];
    *(sx8*)(base + 8) = *(sx8*)&tmp[8];
  } else {
    bf16* dst = v + ((size_t)z * C_ + orow) * N_ + p0 + tid;
    #pragma unroll
    for (int i = 0; i < 16; ++i)
      dst[(size_t)i * N_] = f2b(acc[i] + bias[orow + i]);
  }
}

// ---------------------------------------------------------------------------
// Kernel 2: MFMA flash attention.  S^T = K^T*Q (so softmax stats are per-lane),
// O^T = V*P^T (V natural layout, P^T via cheap wave-private LDS round-trip).
// 128 queries/block, 4 waves x 2 strips of 16; K/V tile = 64.
// grid (N_/128, NH_, 2*B_), block 256
// ---------------------------------------------------------------------------
__global__ __launch_bounds__(256)
void attn_kernel(const bf16* __restrict__ qt, const bf16* __restrict__ kt,
                 const bf16* __restrict__ v, bf16* __restrict__ atto) {
  const int tid  = threadIdx.x;
  const int m0   = blockIdx.x * 128;
  const int h    = blockIdx.y;
  const int ho   = h * D_;
  const int z    = blockIdx.z;          // s*B_ + b
  const int s = z >> 1, b = z & 1;
  const int zo = ((1 - s) << 1) | b;    // kv source

  const bf16* qtz = qt + (size_t)z  * N_ * C_;
  const bf16* ktz = kt + (size_t)zo * N_ * C_;
  const bf16* vz  = v  + (size_t)zo * C_ * N_;

  const int lane = tid & 63;
  const int w    = tid >> 6;            // wave 0..3
  const int ml   = lane & 15;           // MFMA outer index
  const int Q4   = (lane >> 4) * 4;     // quad*4
  const int Q8   = (lane >> 4) * 8;     // quad*8

  // LDS: strides padded for <=2-way conflicts, 16B alignment kept
  __shared__ __align__(16) short kts[64 * 40];        // [n][d(32) pad->40]
  __shared__ __align__(16) short vss[32 * 72];        // [d][n(64) pad->72]
  __shared__ __align__(16) short pst[4][2][16 * 72];  // per wave, per strip: [m][n]

  // Q fragments: B-operand B[k=d][col=m] -> qt[m][d], one 16B load per strip
  sx8 qf[2];
  #pragma unroll
  for (int s2 = 0; s2 < 2; ++s2) {
    int mrow = m0 + w * 32 + s2 * 16 + ml;
    qf[s2] = *(const sx8*)(qtz + (size_t)mrow * C_ + ho + Q8);
  }

  const fx4 z4 = {0.f, 0.f, 0.f, 0.f};
  fx4 acc[2][2] = {{z4, z4}, {z4, z4}};         // [strip][d-tile], O^T[d][m]
  float mst[2] = {-3e38f, -3e38f};
  float lst[2] = {0.f, 0.f};

  for (int n0 = 0; n0 < N_; n0 += 64) {
    __syncthreads();
    {  // stage K tile (straight copy, pos-major) + V tile (natural)
      int nk = tid >> 2, du = (tid & 3) * 8;
      *(sx8*)&kts[nk * 40 + du] =
          *(const sx8*)(ktz + (size_t)(n0 + nk) * C_ + ho + du);
      int dv = tid >> 3, nu = (tid & 7) * 8;
      *(sx8*)&vss[dv * 72 + nu] =
          *(const sx8*)(vz + (size_t)(ho + dv) * N_ + n0 + nu);
    }
    __syncthreads();

    // K fragments (A-operand of S^T): A[row=n][k=d] -> kts[n][d]
    sx8 kf[4];
    #pragma unroll
    for (int t = 0; t < 4; ++t)
      kf[t] = *(sx8*)&kts[(t * 16 + ml) * 40 + Q8];
    // V fragments (A-operand of PV): A[row=d][k=n] -> vss[d][n]
    sx8 vf[2][2];
    #pragma unroll
    for (int dt = 0; dt < 2; ++dt)
      #pragma unroll
      for (int c = 0; c < 2; ++c)
        vf[dt][c] = *(sx8*)&vss[(dt * 16 + ml) * 72 + c * 32 + Q8];

    #pragma unroll
    for (int s2 = 0; s2 < 2; ++s2) {
      // S^T strip: 64n x 16m, n tiles t: rows n=16t+Q4+r, col m=ml
      fx4 st[4];
      #pragma unroll
      for (int t = 0; t < 4; ++t)
        st[t] = __builtin_amdgcn_mfma_f32_16x16x32_bf16(kf[t], qf[s2], z4, 0, 0, 0);

      // online softmax over n (all 16 in-lane values belong to column m=ml)
      float tmax = st[0][0];
      #pragma unroll
      for (int t = 0; t < 4; ++t)
        #pragma unroll
        for (int r = 0; r < 4; ++r) tmax = fmaxf(tmax, st[t][r]);
      tmax = fmaxf(tmax, __shfl_xor(tmax, 16));
      tmax = fmaxf(tmax, __shfl_xor(tmax, 32));
      float mnew  = fmaxf(mst[s2], tmax);
      float alpha = __expf(SCALE_ * (mst[s2] - mnew));
      mst[s2] = mnew;
      float rsum = 0.f;
      #pragma unroll
      for (int t = 0; t < 4; ++t)
        #pragma unroll
        for (int r = 0; r < 4; ++r) {
          float p = __expf(SCALE_ * (st[t][r] - mnew));
          st[t][r] = p;
          rsum += p;
        }
      rsum += __shfl_xor(rsum, 16);
      rsum += __shfl_xor(rsum, 32);
      lst[s2] = lst[s2] * alpha + rsum;

      // P^T -> LDS (pack 4 consecutive n per tile: one b64 write each)
      #pragma unroll
      for (int t = 0; t < 4; ++t) {
        sx4 pk = {fbs(st[t][0]), fbs(st[t][1]), fbs(st[t][2]), fbs(st[t][3])};
        *(sx4*)&pst[w][s2][ml * 72 + t * 16 + Q4] = pk;
      }
      lds_fence();
      // B-operand frags: B[k=n][col=m] -> pst[m][n], 16B contiguous
      sx8 pf0 = *(sx8*)&pst[w][s2][ml * 72 + 0  + Q8];
      sx8 pf1 = *(sx8*)&pst[w][s2][ml * 72 + 32 + Q8];

      // O^T[d][m] = alpha*O^T + V*P^T
      #pragma unroll
      for (int dt = 0; dt < 2; ++dt) {
        fx4 a = acc[s2][dt];
        #pragma unroll
        for (int r = 0; r < 4; ++r) a[r] *= alpha;
        a = __builtin_amdgcn_mfma_f32_16x16x32_bf16(vf[dt][0], pf0, a, 0, 0, 0);
        a = __builtin_amdgcn_mfma_f32_16x16x32_bf16(vf[dt][1], pf1, a, 0, 0, 0);
        acc[s2][dt] = a;
      }
    }
  }

  // epilogue: O^T C-layout row d = dt*16+Q4+r, col m = ml
  #pragma unroll
  for (int s2 = 0; s2 < 2; ++s2) {
    float inv = 1.f / lst[s2];
    int col = m0 + w * 32 + s2 * 16 + ml;
    #pragma unroll
    for (int dt = 0; dt < 2; ++dt)
      #pragma unroll
      for (int r = 0; r < 4; ++r) {
        int d = dt * 16 + Q4 + r;
        atto[((size_t)z * C_ + ho + d) * N_ + col] = f2b(acc[s2][dt][r] * inv);
      }
  }
}

// ---------------------------------------------------------------------------
// Kernel 3: out = spatial + freq + Wo*(attS + attF) + 2*bo
// grid (N_/256, C_/16, B_), block 256
// ---------------------------------------------------------------------------
__global__ __launch_bounds__(256)
void out_proj_kernel(const bf16* __restrict__ atto,
                     const float* __restrict__ spatial,
                     const float* __restrict__ freq,
                     const float* __restrict__ wo, const float* __restrict__ bo,
                     float* __restrict__ out) {
  const int tid = threadIdx.x;
  const int p0 = blockIdx.x * 256;
  const int o0 = blockIdx.y * 16;
  const int b  = blockIdx.z;

  const bf16* a0 = atto + ((size_t)(0 * B_ + b) * C_) * N_;
  const bf16* a1 = atto + ((size_t)(1 * B_ + b) * C_) * N_;

  __shared__ float xs[16][256];
  float acc[16];
  #pragma unroll
  for (int i = 0; i < 16; ++i) acc[i] = 0.f;

  for (int c0 = 0; c0 < C_; c0 += 16) {
    __syncthreads();
    #pragma unroll
    for (int i = 0; i < 16; ++i) {
      size_t off = (size_t)(c0 + i) * N_ + p0 + tid;
      xs[i][tid] = b2f(a0[off]) + b2f(a1[off]);
    }
    __syncthreads();
    #pragma unroll
    for (int kk = 0; kk < 16; ++kk) {
      float xv = xs[kk][tid];
      #pragma unroll
      for (int i = 0; i < 16; ++i)
        acc[i] += wo[(o0 + i) * C_ + c0 + kk] * xv;
    }
  }

  #pragma unroll
  for (int i = 0; i < 16; ++i) {
    size_t off = (size_t)(b * C_ + o0 + i) * N_ + p0 + tid;
    out[off] = acc[i] + 2.f * bo[o0 + i] + spatial[off] + freq[off];
  }
}

extern "C" void kernel_launch(void* const* d_in, const int* in_sizes, int n_in,
                              void* d_out, int out_size, void* d_ws, size_t ws_size,
                              hipStream_t stream) {
  const float* spatial = (const float*)d_in[0];
  const float* freq    = (const float*)d_in[1];
  const float* wq = (const float*)d_in[2];
  const float* bq = (const float*)d_in[3];
  const float* wk = (const float*)d_in[4];
  const float* bk = (const float*)d_in[5];
  const float* wv = (const float*)d_in[6];
  const float* bv = (const float*)d_in[7];
  const float* wo = (const float*)d_in[8];
  const float* bo = (const float*)d_in[9];
  float* out = (float*)d_out;

  // workspace: qt, kt, v, atto — each 4 * N * C bf16 = 8 MB (32 MB total)
  const size_t SZ = (size_t)2 * B_ * N_ * C_;
  bf16* qt   = (bf16*)d_ws;
  bf16* kt   = qt + SZ;
  bf16* v    = kt + SZ;
  bf16* atto = v + SZ;

  qkv_proj_kernel<<<dim3(N_ / 256, 768 / 16, 2 * B_), 256, 0, stream>>>(
      spatial, freq, wq, bq, wk, bk, wv, bv, qt, kt, v);
  attn_kernel<<<dim3(N_ / 128, NH_, 2 * B_), 256, 0, stream>>>(qt, kt, v, atto);
  out_proj_kernel<<<dim3(N_ / 256, C_ / 16, B_), 256, 0, stream>>>(
      atto, spatial, freq, wo, bo, out);
}

// Round 3
// 335.666 us; speedup vs baseline: 8.5293x; 1.7636x over previous
//
#include <hip/hip_runtime.h>
#include <hip/hip_bf16.h>

#define B_ 2
#define C_ 256
#define NH_ 8
#define D_ 32
#define N_ 4096
#define SCALE_ 0.17677669529663689f

typedef __hip_bfloat16 bf16;
typedef __attribute__((ext_vector_type(8))) short sx8;   // 8 bf16 = one MFMA A/B frag
typedef __attribute__((ext_vector_type(4))) short sx4;
typedef __attribute__((ext_vector_type(4))) float fx4;   // MFMA C/D frag

__device__ __forceinline__ float b2f(bf16 x) { return __bfloat162float(x); }
__device__ __forceinline__ bf16 f2b(float x) { return __float2bfloat16(x); }
__device__ __forceinline__ short fbs(float x) { bf16 h = __float2bfloat16(x); return *(short*)&h; }
__device__ __forceinline__ float sbf(short s) { bf16 h = *(bf16*)&s; return __bfloat162float(h); }
__device__ __forceinline__ void lds_fence() { asm volatile("s_waitcnt lgkmcnt(0)" ::: "memory"); }

// ---------------------------------------------------------------------------
// Prep 1: x (fp32, c-major) -> xb[z][p][c] bf16 pos-major (transpose+convert)
// grid (N_/64, C_/64, 2*B_), block 256
// ---------------------------------------------------------------------------
__global__ __launch_bounds__(256)
void convert_x_kernel(const float* __restrict__ spatial,
                      const float* __restrict__ freq,
                      bf16* __restrict__ xb) {
  const int tid = threadIdx.x;
  const int p0 = blockIdx.x * 64;
  const int c0 = blockIdx.y * 64;
  const int z  = blockIdx.z;            // s*B_ + b
  const int s = z >> 1, b = z & 1;
  const float* x = (s == 0) ? spatial : freq;

  __shared__ float ls[64][65];

  const int pp = tid & 63, cb = tid >> 6;
  #pragma unroll
  for (int i = 0; i < 16; ++i) {
    int c = cb + 4 * i;
    ls[c][pp] = x[(size_t)(b * C_ + c0 + c) * N_ + p0 + pp];
  }
  __syncthreads();

  #pragma unroll
  for (int i = 0; i < 2; ++i) {
    int j = tid + 256 * i;              // 0..511
    int p = j >> 3, ck = (j & 7) * 8;
    short tmp[8];
    #pragma unroll
    for (int u = 0; u < 8; ++u) tmp[u] = fbs(ls[ck + u][p]);
    *(sx8*)(xb + ((size_t)z * N_ + p0 + p) * C_ + c0 + ck) = *(sx8*)tmp;
  }
}

// ---------------------------------------------------------------------------
// Prep 2: weights -> bf16. wb = stacked [wq;wk;wv] (768x256), wob = wo.
// grid (1024), block 256
// ---------------------------------------------------------------------------
__global__ __launch_bounds__(256)
void convert_w_kernel(const float* __restrict__ wq, const float* __restrict__ wk,
                      const float* __restrict__ wv, const float* __restrict__ wo,
                      bf16* __restrict__ wb, bf16* __restrict__ wob) {
  int idx = blockIdx.x * 256 + threadIdx.x;     // 0..262143
  if (idx < 196608) {
    const float* src = (idx < 65536) ? wq : (idx < 131072) ? wk : wv;
    wb[idx] = f2b(src[idx & 65535]);
  } else {
    int off = idx - 196608;
    wob[off] = f2b(wo[off]);
  }
}

// ---------------------------------------------------------------------------
// Kernel 1: QKV projection as MFMA GEMM. D = W (768x256) * x (256x4096) per z.
// qt/kt pos-major [z][p][c]; v d-major [z][c][p].
// grid (N_/128, 768/128, 2*B_), block 256 (4 waves, each 64x64)
// ---------------------------------------------------------------------------
__global__ __launch_bounds__(256)
void qkv_gemm_kernel(const bf16* __restrict__ wb, const bf16* __restrict__ xb,
                     const float* __restrict__ bq, const float* __restrict__ bk,
                     const float* __restrict__ bv,
                     bf16* __restrict__ qt, bf16* __restrict__ kt,
                     bf16* __restrict__ v) {
  const int tid = threadIdx.x;
  const int p0 = blockIdx.x * 128;
  const int o0 = blockIdx.y * 128;
  const int z  = blockIdx.z;

  const int lane = tid & 63, w = tid >> 6;
  const int ml = lane & 15, Q4 = (lane >> 4) * 4, Q8 = (lane >> 4) * 8;
  const int ow = (w >> 1) * 64, pw = (w & 1) * 64;

  __shared__ __align__(16) short asb[128 * 72];
  __shared__ __align__(16) short bsb[128 * 72];
  __shared__ float bias_s[128];

  if (tid < 128) {
    int o = o0 + tid;
    bias_s[tid] = (o < 256) ? bq[o] : (o < 512) ? bk[o - 256] : bv[o - 512];
  }

  const fx4 z4 = {0.f, 0.f, 0.f, 0.f};
  fx4 acc[4][4];
  #pragma unroll
  for (int ot = 0; ot < 4; ++ot)
    #pragma unroll
    for (int pt = 0; pt < 4; ++pt) acc[ot][pt] = z4;

  const int sr = tid >> 1, scu = (tid & 1) * 32;
  for (int k0 = 0; k0 < 256; k0 += 64) {
    __syncthreads();
    #pragma unroll
    for (int u = 0; u < 4; ++u) {
      *(sx8*)&asb[sr * 72 + scu + u * 8] =
          *(const sx8*)&wb[(o0 + sr) * 256 + k0 + scu + u * 8];
      *(sx8*)&bsb[sr * 72 + scu + u * 8] =
          *(const sx8*)(xb + ((size_t)z * N_ + p0 + sr) * C_ + k0 + scu + u * 8);
    }
    __syncthreads();
    #pragma unroll
    for (int kk = 0; kk < 2; ++kk) {
      sx8 af[4], bfr[4];
      #pragma unroll
      for (int t = 0; t < 4; ++t)
        af[t] = *(sx8*)&asb[(ow + t * 16 + ml) * 72 + kk * 32 + Q8];
      #pragma unroll
      for (int t = 0; t < 4; ++t)
        bfr[t] = *(sx8*)&bsb[(pw + t * 16 + ml) * 72 + kk * 32 + Q8];
      #pragma unroll
      for (int ot = 0; ot < 4; ++ot)
        #pragma unroll
        for (int pt = 0; pt < 4; ++pt)
          acc[ot][pt] = __builtin_amdgcn_mfma_f32_16x16x32_bf16(
              af[ot], bfr[pt], acc[ot][pt], 0, 0, 0);
    }
  }

  if (o0 < 512) {
    // Q or K rows: pos-major store, 4 consecutive o = contiguous b64
    bf16* dst0 = (o0 < 256) ? qt : kt;
    const int obase = (o0 < 256) ? o0 : o0 - 256;
    #pragma unroll
    for (int ot = 0; ot < 4; ++ot) {
      const int ol = ow + ot * 16 + Q4;
      #pragma unroll
      for (int pt = 0; pt < 4; ++pt) {
        int p = p0 + pw + pt * 16 + ml;
        short tmp[4];
        #pragma unroll
        for (int r = 0; r < 4; ++r)
          tmp[r] = fbs(acc[ot][pt][r] + bias_s[ol + r]);
        *(sx4*)(dst0 + ((size_t)z * N_ + p) * C_ + obase + ol) = *(sx4*)tmp;
      }
    }
  } else {
    // V rows: d-major store (attention PV wants natural (d,n))
    #pragma unroll
    for (int ot = 0; ot < 4; ++ot)
      #pragma unroll
      for (int pt = 0; pt < 4; ++pt) {
        int p = p0 + pw + pt * 16 + ml;
        #pragma unroll
        for (int r = 0; r < 4; ++r) {
          int ol = ow + ot * 16 + Q4 + r;
          v[((size_t)z * C_ + (o0 - 512) + ol) * N_ + p] =
              f2b(acc[ot][pt][r] + bias_s[ol]);
        }
      }
  }
}

// ---------------------------------------------------------------------------
// Kernel 2: MFMA flash attention (unchanged core; epilogue now writes
// attoT[z][p][c] pos-major with b64 stores).
// grid (N_/128, NH_, 2*B_), block 256
// ---------------------------------------------------------------------------
__global__ __launch_bounds__(256)
void attn_kernel(const bf16* __restrict__ qt, const bf16* __restrict__ kt,
                 const bf16* __restrict__ v, bf16* __restrict__ attoT) {
  const int tid  = threadIdx.x;
  const int m0   = blockIdx.x * 128;
  const int h    = blockIdx.y;
  const int ho   = h * D_;
  const int z    = blockIdx.z;          // s*B_ + b
  const int s = z >> 1, b = z & 1;
  const int zo = ((1 - s) << 1) | b;    // kv source

  const bf16* qtz = qt + (size_t)z  * N_ * C_;
  const bf16* ktz = kt + (size_t)zo * N_ * C_;
  const bf16* vz  = v  + (size_t)zo * C_ * N_;

  const int lane = tid & 63;
  const int w    = tid >> 6;
  const int ml   = lane & 15;
  const int Q4   = (lane >> 4) * 4;
  const int Q8   = (lane >> 4) * 8;

  __shared__ __align__(16) short kts[64 * 40];        // [n][d pad->40]
  __shared__ __align__(16) short vss[32 * 72];        // [d][n pad->72]
  __shared__ __align__(16) short pst[4][2][16 * 72];  // per wave/strip: [m][n]

  sx8 qf[2];
  #pragma unroll
  for (int s2 = 0; s2 < 2; ++s2) {
    int mrow = m0 + w * 32 + s2 * 16 + ml;
    qf[s2] = *(const sx8*)(qtz + (size_t)mrow * C_ + ho + Q8);
  }

  const fx4 z4 = {0.f, 0.f, 0.f, 0.f};
  fx4 acc[2][2] = {{z4, z4}, {z4, z4}};
  float mst[2] = {-3e38f, -3e38f};
  float lst[2] = {0.f, 0.f};

  for (int n0 = 0; n0 < N_; n0 += 64) {
    __syncthreads();
    {
      int nk = tid >> 2, du = (tid & 3) * 8;
      *(sx8*)&kts[nk * 40 + du] =
          *(const sx8*)(ktz + (size_t)(n0 + nk) * C_ + ho + du);
      int dv = tid >> 3, nu = (tid & 7) * 8;
      *(sx8*)&vss[dv * 72 + nu] =
          *(const sx8*)(vz + (size_t)(ho + dv) * N_ + n0 + nu);
    }
    __syncthreads();

    sx8 kf[4];
    #pragma unroll
    for (int t = 0; t < 4; ++t)
      kf[t] = *(sx8*)&kts[(t * 16 + ml) * 40 + Q8];
    sx8 vf[2][2];
    #pragma unroll
    for (int dt = 0; dt < 2; ++dt)
      #pragma unroll
      for (int c = 0; c < 2; ++c)
        vf[dt][c] = *(sx8*)&vss[(dt * 16 + ml) * 72 + c * 32 + Q8];

    #pragma unroll
    for (int s2 = 0; s2 < 2; ++s2) {
      fx4 st[4];
      #pragma unroll
      for (int t = 0; t < 4; ++t)
        st[t] = __builtin_amdgcn_mfma_f32_16x16x32_bf16(kf[t], qf[s2], z4, 0, 0, 0);

      float tmax = st[0][0];
      #pragma unroll
      for (int t = 0; t < 4; ++t)
        #pragma unroll
        for (int r = 0; r < 4; ++r) tmax = fmaxf(tmax, st[t][r]);
      tmax = fmaxf(tmax, __shfl_xor(tmax, 16));
      tmax = fmaxf(tmax, __shfl_xor(tmax, 32));
      float mnew  = fmaxf(mst[s2], tmax);
      float alpha = __expf(SCALE_ * (mst[s2] - mnew));
      mst[s2] = mnew;
      float rsum = 0.f;
      #pragma unroll
      for (int t = 0; t < 4; ++t)
        #pragma unroll
        for (int r = 0; r < 4; ++r) {
          float p = __expf(SCALE_ * (st[t][r] - mnew));
          st[t][r] = p;
          rsum += p;
        }
      rsum += __shfl_xor(rsum, 16);
      rsum += __shfl_xor(rsum, 32);
      lst[s2] = lst[s2] * alpha + rsum;

      #pragma unroll
      for (int t = 0; t < 4; ++t) {
        sx4 pk = {fbs(st[t][0]), fbs(st[t][1]), fbs(st[t][2]), fbs(st[t][3])};
        *(sx4*)&pst[w][s2][ml * 72 + t * 16 + Q4] = pk;
      }
      lds_fence();
      sx8 pf0 = *(sx8*)&pst[w][s2][ml * 72 + 0  + Q8];
      sx8 pf1 = *(sx8*)&pst[w][s2][ml * 72 + 32 + Q8];

      #pragma unroll
      for (int dt = 0; dt < 2; ++dt) {
        fx4 a = acc[s2][dt];
        #pragma unroll
        for (int r = 0; r < 4; ++r) a[r] *= alpha;
        a = __builtin_amdgcn_mfma_f32_16x16x32_bf16(vf[dt][0], pf0, a, 0, 0, 0);
        a = __builtin_amdgcn_mfma_f32_16x16x32_bf16(vf[dt][1], pf1, a, 0, 0, 0);
        acc[s2][dt] = a;
      }
    }
  }

  // epilogue: pos-major attoT[z][p][c], 4 consecutive d = contiguous b64
  #pragma unroll
  for (int s2 = 0; s2 < 2; ++s2) {
    float inv = 1.f / lst[s2];
    int col = m0 + w * 32 + s2 * 16 + ml;
    #pragma unroll
    for (int dt = 0; dt < 2; ++dt) {
      short tmp[4];
      #pragma unroll
      for (int r = 0; r < 4; ++r) tmp[r] = fbs(acc[s2][dt][r] * inv);
      *(sx4*)(attoT + ((size_t)z * N_ + col) * C_ + ho + dt * 16 + Q4) =
          *(sx4*)tmp;
    }
  }
}

// ---------------------------------------------------------------------------
// Kernel 3: out_proj as MFMA GEMM. D = Wo * (attS + attF), residuals fused.
// grid (N_/128, 256/64, B_), block 256 (4 waves, each 32x64)
// ---------------------------------------------------------------------------
__global__ __launch_bounds__(256)
void out_proj_kernel(const bf16* __restrict__ wob, const bf16* __restrict__ attoT,
                     const float* __restrict__ spatial,
                     const float* __restrict__ freq,
                     const float* __restrict__ bo, float* __restrict__ out) {
  const int tid = threadIdx.x;
  const int p0 = blockIdx.x * 128;
  const int o0 = blockIdx.y * 64;
  const int b  = blockIdx.z;

  const int lane = tid & 63, w = tid >> 6;
  const int ml = lane & 15, Q4 = (lane >> 4) * 4, Q8 = (lane >> 4) * 8;
  const int ow = (w >> 1) * 32, pw = (w & 1) * 64;

  __shared__ __align__(16) short asb[64 * 72];
  __shared__ __align__(16) short bsb[128 * 72];
  __shared__ float bo_s[64];

  if (tid < 64) bo_s[tid] = 2.f * bo[o0 + tid];

  const bf16* at0 = attoT + (size_t)(0 + b) * N_ * C_;   // s=0 slice
  const bf16* at1 = attoT + (size_t)(2 + b) * N_ * C_;   // s=1 slice

  const fx4 z4 = {0.f, 0.f, 0.f, 0.f};
  fx4 acc[2][4];
  #pragma unroll
  for (int ot = 0; ot < 2; ++ot)
    #pragma unroll
    for (int pt = 0; pt < 4; ++pt) acc[ot][pt] = z4;

  for (int k0 = 0; k0 < 256; k0 += 64) {
    __syncthreads();
    #pragma unroll
    for (int i = 0; i < 2; ++i) {
      int j = tid + 256 * i;            // 0..511
      int r = j >> 3, cu = (j & 7) * 8;
      *(sx8*)&asb[r * 72 + cu] = *(const sx8*)&wob[(o0 + r) * 256 + k0 + cu];
    }
    #pragma unroll
    for (int i = 0; i < 4; ++i) {
      int j = tid + 256 * i;            // 0..1023
      int p = j >> 3, cu = (j & 7) * 8;
      sx8 va = *(const sx8*)(at0 + (size_t)(p0 + p) * C_ + k0 + cu);
      sx8 vb2 = *(const sx8*)(at1 + (size_t)(p0 + p) * C_ + k0 + cu);
      short tmp[8];
      #pragma unroll
      for (int u = 0; u < 8; ++u) tmp[u] = fbs(sbf(va[u]) + sbf(vb2[u]));
      *(sx8*)&bsb[p * 72 + cu] = *(sx8*)tmp;
    }
    __syncthreads();
    #pragma unroll
    for (int kk = 0; kk < 2; ++kk) {
      sx8 af[2], bfr[4];
      #pragma unroll
      for (int t = 0; t < 2; ++t)
        af[t] = *(sx8*)&asb[(ow + t * 16 + ml) * 72 + kk * 32 + Q8];
      #pragma unroll
      for (int t = 0; t < 4; ++t)
        bfr[t] = *(sx8*)&bsb[(pw + t * 16 + ml) * 72 + kk * 32 + Q8];
      #pragma unroll
      for (int ot = 0; ot < 2; ++ot)
        #pragma unroll
        for (int pt = 0; pt < 4; ++pt)
          acc[ot][pt] = __builtin_amdgcn_mfma_f32_16x16x32_bf16(
              af[ot], bfr[pt], acc[ot][pt], 0, 0, 0);
    }
  }

  #pragma unroll
  for (int ot = 0; ot < 2; ++ot)
    #pragma unroll
    for (int pt = 0; pt < 4; ++pt) {
      int p = p0 + pw + pt * 16 + ml;
      #pragma unroll
      for (int r = 0; r < 4; ++r) {
        int ol = ow + ot * 16 + Q4 + r;
        size_t off = ((size_t)b * C_ + o0 + ol) * N_ + p;
        out[off] = acc[ot][pt][r] + bo_s[ol] + spatial[off] + freq[off];
      }
    }
}

extern "C" void kernel_launch(void* const* d_in, const int* in_sizes, int n_in,
                              void* d_out, int out_size, void* d_ws, size_t ws_size,
                              hipStream_t stream) {
  const float* spatial = (const float*)d_in[0];
  const float* freq    = (const float*)d_in[1];
  const float* wq = (const float*)d_in[2];
  const float* bq = (const float*)d_in[3];
  const float* wk = (const float*)d_in[4];
  const float* bk = (const float*)d_in[5];
  const float* wv = (const float*)d_in[6];
  const float* bv = (const float*)d_in[7];
  const float* wo = (const float*)d_in[8];
  const float* bo = (const float*)d_in[9];
  float* out = (float*)d_out;

  // workspace layout (bf16 elements)
  const size_t SZ = (size_t)2 * B_ * N_ * C_;   // 4M elems = 8 MB
  bf16* xb    = (bf16*)d_ws;                    // [z][p][c]
  bf16* qt    = xb + SZ;                        // [z][p][c]
  bf16* kt    = qt + SZ;                        // [z][p][c]
  bf16* v     = kt + SZ;                        // [z][c][p]
  bf16* attoT = v + SZ;                         // [z][p][c]
  bf16* wb    = attoT + SZ;                     // [768][256]
  bf16* wob   = wb + 768 * 256;                 // [256][256]

  convert_w_kernel<<<dim3(1024), 256, 0, stream>>>(wq, wk, wv, wo, wb, wob);
  convert_x_kernel<<<dim3(N_ / 64, C_ / 64, 2 * B_), 256, 0, stream>>>(
      spatial, freq, xb);
  qkv_gemm_kernel<<<dim3(N_ / 128, 768 / 128, 2 * B_), 256, 0, stream>>>(
      wb, xb, bq, bk, bv, qt, kt, v);
  attn_kernel<<<dim3(N_ / 128, NH_, 2 * B_), 256, 0, stream>>>(qt, kt, v, attoT);
  out_proj_kernel<<<dim3(N_ / 128, C_ / 64, B_), 256, 0, stream>>>(
      wob, attoT, spatial, freq, bo, out);
}

// Round 4
// 235.215 us; speedup vs baseline: 12.1718x; 1.4271x over previous
//
#include <hip/hip_runtime.h>
#include <hip/hip_bf16.h>

#define B_ 2
#define C_ 256
#define NH_ 8
#define D_ 32
#define N_ 4096
#define SCALE_ 0.17677669529663689f
// SCALE * log2(e): folded into Q so softmax is a bare v_exp_f32 per score
#define QSC_ 0.25505277f

typedef __hip_bfloat16 bf16;
typedef __attribute__((ext_vector_type(8))) short sx8;   // 8 bf16 = one MFMA A/B frag
typedef __attribute__((ext_vector_type(4))) short sx4;
typedef __attribute__((ext_vector_type(4))) float fx4;   // MFMA C/D frag

__device__ __forceinline__ float b2f(bf16 x) { return __bfloat162float(x); }
__device__ __forceinline__ bf16 f2b(float x) { return __float2bfloat16(x); }
__device__ __forceinline__ short fbs(float x) { bf16 h = __float2bfloat16(x); return *(short*)&h; }
__device__ __forceinline__ float sbf(short s) { bf16 h = *(bf16*)&s; return __bfloat162float(h); }
__device__ __forceinline__ void lds_fence() { asm volatile("s_waitcnt lgkmcnt(0)" ::: "memory"); }

#if __has_builtin(__builtin_amdgcn_exp2f)
__device__ __forceinline__ float fexp2(float x) { return __builtin_amdgcn_exp2f(x); }
#else
__device__ __forceinline__ float fexp2(float x) { return exp2f(x); }
#endif

// ---------------------------------------------------------------------------
// Prep 1: x (fp32, c-major) -> xb[z][p][c] bf16 pos-major (transpose+convert)
// grid (N_/64, C_/64, 2*B_), block 256
// ---------------------------------------------------------------------------
__global__ __launch_bounds__(256)
void convert_x_kernel(const float* __restrict__ spatial,
                      const float* __restrict__ freq,
                      bf16* __restrict__ xb) {
  const int tid = threadIdx.x;
  const int p0 = blockIdx.x * 64;
  const int c0 = blockIdx.y * 64;
  const int z  = blockIdx.z;            // s*B_ + b
  const int s = z >> 1, b = z & 1;
  const float* x = (s == 0) ? spatial : freq;

  __shared__ float ls[64][65];

  const int pp = tid & 63, cb = tid >> 6;
  #pragma unroll
  for (int i = 0; i < 16; ++i) {
    int c = cb + 4 * i;
    ls[c][pp] = x[(size_t)(b * C_ + c0 + c) * N_ + p0 + pp];
  }
  __syncthreads();

  #pragma unroll
  for (int i = 0; i < 2; ++i) {
    int j = tid + 256 * i;              // 0..511
    int p = j >> 3, ck = (j & 7) * 8;
    short tmp[8];
    #pragma unroll
    for (int u = 0; u < 8; ++u) tmp[u] = fbs(ls[ck + u][p]);
    *(sx8*)(xb + ((size_t)z * N_ + p0 + p) * C_ + c0 + ck) = *(sx8*)tmp;
  }
}

// ---------------------------------------------------------------------------
// Prep 2: weights -> bf16. wb = stacked [wq;wk;wv] (768x256), wob = wo.
// grid (1024), block 256
// ---------------------------------------------------------------------------
__global__ __launch_bounds__(256)
void convert_w_kernel(const float* __restrict__ wq, const float* __restrict__ wk,
                      const float* __restrict__ wv, const float* __restrict__ wo,
                      bf16* __restrict__ wb, bf16* __restrict__ wob) {
  int idx = blockIdx.x * 256 + threadIdx.x;     // 0..262143
  if (idx < 196608) {
    const float* src = (idx < 65536) ? wq : (idx < 131072) ? wk : wv;
    wb[idx] = f2b(src[idx & 65535]);
  } else {
    int off = idx - 196608;
    wob[off] = f2b(wo[off]);
  }
}

// ---------------------------------------------------------------------------
// Kernel 1: QKV projection as MFMA GEMM. D = W (768x256) * x (256x4096) per z.
// Outputs (all laid out so attention frag loads are 1KB-contiguous per wave):
//   qhf/khf: per-head pos-major [z][h][n][d32]   (Q pre-scaled by QSC_)
//   vhf:     frag-blocked [z][h][n>>5][d>>4][d&15][n&31]
// grid (N_/128, 768/128, 2*B_), block 256 (4 waves, each 64x64)
// ---------------------------------------------------------------------------
__global__ __launch_bounds__(256)
void qkv_gemm_kernel(const bf16* __restrict__ wb, const bf16* __restrict__ xb,
                     const float* __restrict__ bq, const float* __restrict__ bk,
                     const float* __restrict__ bv,
                     bf16* __restrict__ qhf, bf16* __restrict__ khf,
                     bf16* __restrict__ vhf) {
  const int tid = threadIdx.x;
  const int p0 = blockIdx.x * 128;
  const int o0 = blockIdx.y * 128;
  const int z  = blockIdx.z;

  const int lane = tid & 63, w = tid >> 6;
  const int ml = lane & 15, Q4 = (lane >> 4) * 4, Q8 = (lane >> 4) * 8;
  const int ow = (w >> 1) * 64, pw = (w & 1) * 64;

  __shared__ __align__(16) short asb[128 * 72];
  __shared__ __align__(16) short bsb[128 * 72];
  __shared__ float bias_s[128];

  if (tid < 128) {
    int o = o0 + tid;
    bias_s[tid] = (o < 256) ? bq[o] : (o < 512) ? bk[o - 256] : bv[o - 512];
  }

  const fx4 z4 = {0.f, 0.f, 0.f, 0.f};
  fx4 acc[4][4];
  #pragma unroll
  for (int ot = 0; ot < 4; ++ot)
    #pragma unroll
    for (int pt = 0; pt < 4; ++pt) acc[ot][pt] = z4;

  const int sr = tid >> 1, scu = (tid & 1) * 32;
  for (int k0 = 0; k0 < 256; k0 += 64) {
    __syncthreads();
    #pragma unroll
    for (int u = 0; u < 4; ++u) {
      *(sx8*)&asb[sr * 72 + scu + u * 8] =
          *(const sx8*)&wb[(o0 + sr) * 256 + k0 + scu + u * 8];
      *(sx8*)&bsb[sr * 72 + scu + u * 8] =
          *(const sx8*)(xb + ((size_t)z * N_ + p0 + sr) * C_ + k0 + scu + u * 8);
    }
    __syncthreads();
    #pragma unroll
    for (int kk = 0; kk < 2; ++kk) {
      sx8 af[4], bfr[4];
      #pragma unroll
      for (int t = 0; t < 4; ++t)
        af[t] = *(sx8*)&asb[(ow + t * 16 + ml) * 72 + kk * 32 + Q8];
      #pragma unroll
      for (int t = 0; t < 4; ++t)
        bfr[t] = *(sx8*)&bsb[(pw + t * 16 + ml) * 72 + kk * 32 + Q8];
      #pragma unroll
      for (int ot = 0; ot < 4; ++ot)
        #pragma unroll
        for (int pt = 0; pt < 4; ++pt)
          acc[ot][pt] = __builtin_amdgcn_mfma_f32_16x16x32_bf16(
              af[ot], bfr[pt], acc[ot][pt], 0, 0, 0);
    }
  }

  if (o0 < 512) {
    // Q or K: per-head pos-major [z][h][n][d32]; 4 consecutive o stay in-head
    bf16* dst = (o0 < 256) ? qhf : khf;
    const int ob = (o0 < 256) ? o0 : o0 - 256;
    const float scl = (o0 < 256) ? QSC_ : 1.f;
    #pragma unroll
    for (int ot = 0; ot < 4; ++ot) {
      const int og = ob + ow + ot * 16 + Q4;    // global o, head = og>>5
      #pragma unroll
      for (int pt = 0; pt < 4; ++pt) {
        int p = p0 + pw + pt * 16 + ml;
        short tmp[4];
        #pragma unroll
        for (int r = 0; r < 4; ++r)
          tmp[r] = fbs((acc[ot][pt][r] + bias_s[ow + ot * 16 + Q4 + r]) * scl);
        *(sx4*)(dst + (((size_t)z * NH_ + (og >> 5)) * N_ + p) * D_ + (og & 31)) =
            *(sx4*)tmp;
      }
    }
  } else {
    // V frag-blocked: [z][h][n>>5][d>>4][d&15][n&31]
    #pragma unroll
    for (int ot = 0; ot < 4; ++ot)
      #pragma unroll
      for (int pt = 0; pt < 4; ++pt) {
        int p = p0 + pw + pt * 16 + ml;
        #pragma unroll
        for (int r = 0; r < 4; ++r) {
          int rho = (o0 - 512) + ow + ot * 16 + Q4 + r;   // 0..255
          int h = rho >> 5, d = rho & 31;
          size_t basev = ((size_t)z * NH_ + h) * D_ * N_;
          vhf[basev + (size_t)(((p >> 5) * 2) + (d >> 4)) * 512 +
              (d & 15) * 32 + (p & 31)] =
              f2b(acc[ot][pt][r] + bias_s[(o0 - 512) - (o0 - 512) + ow + ot * 16 + Q4 + r]);
        }
      }
  }
}

// ---------------------------------------------------------------------------
// Kernel 2: MFMA flash attention, wave-independent (NO block barriers).
// K/V fragments read directly from global (1KB contiguous per wave, L1/L2-hit).
// Max-free softmax: Q pre-scaled by QSC_, p = exp2(score), l reduced at end.
// LDS only for the wave-private P^T round-trip.
// grid (N_/128, NH_, 2*B_), block 256 (4 waves x 32 queries)
// ---------------------------------------------------------------------------
__global__ __launch_bounds__(256)
void attn_kernel(const bf16* __restrict__ qhf, const bf16* __restrict__ khf,
                 const bf16* __restrict__ vhf, bf16* __restrict__ attoT) {
  const int tid  = threadIdx.x;
  const int m0   = blockIdx.x * 128;
  const int h    = blockIdx.y;
  const int z    = blockIdx.z;          // s*B_ + b
  const int s = z >> 1, b = z & 1;
  const int zo = ((1 - s) << 1) | b;    // kv source

  const bf16* qz = qhf + ((size_t)z  * NH_ + h) * N_ * D_;
  const bf16* kz = khf + ((size_t)zo * NH_ + h) * N_ * D_;
  const bf16* vz = vhf + ((size_t)zo * NH_ + h) * D_ * N_;

  const int lane = tid & 63;
  const int w    = tid >> 6;
  const int ml   = lane & 15;
  const int Q4   = (lane >> 4) * 4;
  const int Q8   = (lane >> 4) * 8;

  __shared__ __align__(16) short pst[4][2][16 * 72];  // wave-private P^T

  // Q fragments (B-operand): 16 consecutive rows x 64B = 1KB contiguous
  sx8 qf[2];
  #pragma unroll
  for (int s2 = 0; s2 < 2; ++s2)
    qf[s2] = *(const sx8*)(qz + (size_t)(m0 + w * 32 + s2 * 16 + ml) * D_ + Q8);

  const fx4 z4 = {0.f, 0.f, 0.f, 0.f};
  fx4 acc[2][2] = {{z4, z4}, {z4, z4}};
  float lsum[2] = {0.f, 0.f};

  for (int n0 = 0; n0 < N_; n0 += 64) {
    // K fragments (A-operand of S^T): 1KB contiguous per tile
    sx8 kf[4];
    #pragma unroll
    for (int t = 0; t < 4; ++t)
      kf[t] = *(const sx8*)(kz + (size_t)(n0 + t * 16 + ml) * D_ + Q8);
    // V fragments (A-operand of PV): frag-blocked, 1KB contiguous each
    sx8 vf[2][2];
    #pragma unroll
    for (int dt = 0; dt < 2; ++dt)
      #pragma unroll
      for (int c = 0; c < 2; ++c)
        vf[dt][c] = *(const sx8*)(vz + (size_t)(((n0 >> 5) + c) * 2 + dt) * 512 +
                                  ml * 32 + Q8);

    #pragma unroll
    for (int s2 = 0; s2 < 2; ++s2) {
      fx4 st[4];
      #pragma unroll
      for (int t = 0; t < 4; ++t)
        st[t] = __builtin_amdgcn_mfma_f32_16x16x32_bf16(kf[t], qf[s2], z4, 0, 0, 0);

      // max-free softmax: p = 2^score (QSC_ folded into Q), lane-local l
      float rsum = 0.f;
      #pragma unroll
      for (int t = 0; t < 4; ++t)
        #pragma unroll
        for (int r = 0; r < 4; ++r) {
          float p = fexp2(st[t][r]);
          st[t][r] = p;
          rsum += p;
        }
      lsum[s2] += rsum;

      // P^T -> wave-private LDS (b64 writes), read back as B-operand frags
      #pragma unroll
      for (int t = 0; t < 4; ++t) {
        sx4 pk = {fbs(st[t][0]), fbs(st[t][1]), fbs(st[t][2]), fbs(st[t][3])};
        *(sx4*)&pst[w][s2][ml * 72 + t * 16 + Q4] = pk;
      }
      lds_fence();
      sx8 pf0 = *(sx8*)&pst[w][s2][ml * 72 + 0  + Q8];
      sx8 pf1 = *(sx8*)&pst[w][s2][ml * 72 + 32 + Q8];

      #pragma unroll
      for (int dt = 0; dt < 2; ++dt) {
        fx4 a = acc[s2][dt];
        a = __builtin_amdgcn_mfma_f32_16x16x32_bf16(vf[dt][0], pf0, a, 0, 0, 0);
        a = __builtin_amdgcn_mfma_f32_16x16x32_bf16(vf[dt][1], pf1, a, 0, 0, 0);
        acc[s2][dt] = a;
      }
    }
  }

  // epilogue: finish l reduction (4 quad-lanes per column), store pos-major
  #pragma unroll
  for (int s2 = 0; s2 < 2; ++s2) {
    float l = lsum[s2];
    l += __shfl_xor(l, 16);
    l += __shfl_xor(l, 32);
    float inv = 1.f / l;
    int col = m0 + w * 32 + s2 * 16 + ml;
    #pragma unroll
    for (int dt = 0; dt < 2; ++dt) {
      short tmp[4];
      #pragma unroll
      for (int r = 0; r < 4; ++r) tmp[r] = fbs(acc[s2][dt][r] * inv);
      *(sx4*)(attoT + ((size_t)z * N_ + col) * C_ + h * D_ + dt * 16 + Q4) =
          *(sx4*)tmp;
    }
  }
}

// ---------------------------------------------------------------------------
// Kernel 3: out_proj as MFMA GEMM. D = Wo * (attS + attF), residuals fused.
// grid (N_/128, 256/64, B_), block 256 (4 waves, each 32x64)
// ---------------------------------------------------------------------------
__global__ __launch_bounds__(256)
void out_proj_kernel(const bf16* __restrict__ wob, const bf16* __restrict__ attoT,
                     const float* __restrict__ spatial,
                     const float* __restrict__ freq,
                     const float* __restrict__ bo, float* __restrict__ out) {
  const int tid = threadIdx.x;
  const int p0 = blockIdx.x * 128;
  const int o0 = blockIdx.y * 64;
  const int b  = blockIdx.z;

  const int lane = tid & 63, w = tid >> 6;
  const int ml = lane & 15, Q4 = (lane >> 4) * 4, Q8 = (lane >> 4) * 8;
  const int ow = (w >> 1) * 32, pw = (w & 1) * 64;

  __shared__ __align__(16) short asb[64 * 72];
  __shared__ __align__(16) short bsb[128 * 72];
  __shared__ float bo_s[64];

  if (tid < 64) bo_s[tid] = 2.f * bo[o0 + tid];

  const bf16* at0 = attoT + (size_t)(0 + b) * N_ * C_;   // s=0 slice
  const bf16* at1 = attoT + (size_t)(2 + b) * N_ * C_;   // s=1 slice

  const fx4 z4 = {0.f, 0.f, 0.f, 0.f};
  fx4 acc[2][4];
  #pragma unroll
  for (int ot = 0; ot < 2; ++ot)
    #pragma unroll
    for (int pt = 0; pt < 4; ++pt) acc[ot][pt] = z4;

  for (int k0 = 0; k0 < 256; k0 += 64) {
    __syncthreads();
    #pragma unroll
    for (int i = 0; i < 2; ++i) {
      int j = tid + 256 * i;            // 0..511
      int r = j >> 3, cu = (j & 7) * 8;
      *(sx8*)&asb[r * 72 + cu] = *(const sx8*)&wob[(o0 + r) * 256 + k0 + cu];
    }
    #pragma unroll
    for (int i = 0; i < 4; ++i) {
      int j = tid + 256 * i;            // 0..1023
      int p = j >> 3, cu = (j & 7) * 8;
      sx8 va = *(const sx8*)(at0 + (size_t)(p0 + p) * C_ + k0 + cu);
      sx8 vb2 = *(const sx8*)(at1 + (size_t)(p0 + p) * C_ + k0 + cu);
      short tmp[8];
      #pragma unroll
      for (int u = 0; u < 8; ++u) tmp[u] = fbs(sbf(va[u]) + sbf(vb2[u]));
      *(sx8*)&bsb[p * 72 + cu] = *(sx8*)tmp;
    }
    __syncthreads();
    #pragma unroll
    for (int kk = 0; kk < 2; ++kk) {
      sx8 af[2], bfr[4];
      #pragma unroll
      for (int t = 0; t < 2; ++t)
        af[t] = *(sx8*)&asb[(ow + t * 16 + ml) * 72 + kk * 32 + Q8];
      #pragma unroll
      for (int t = 0; t < 4; ++t)
        bfr[t] = *(sx8*)&bsb[(pw + t * 16 + ml) * 72 + kk * 32 + Q8];
      #pragma unroll
      for (int ot = 0; ot < 2; ++ot)
        #pragma unroll
        for (int pt = 0; pt < 4; ++pt)
          acc[ot][pt] = __builtin_amdgcn_mfma_f32_16x16x32_bf16(
              af[ot], bfr[pt], acc[ot][pt], 0, 0, 0);
    }
  }

  #pragma unroll
  for (int ot = 0; ot < 2; ++ot)
    #pragma unroll
    for (int pt = 0; pt < 4; ++pt) {
      int p = p0 + pw + pt * 16 + ml;
      #pragma unroll
      for (int r = 0; r < 4; ++r) {
        int ol = ow + ot * 16 + Q4 + r;
        size_t off = ((size_t)b * C_ + o0 + ol) * N_ + p;
        out[off] = acc[ot][pt][r] + bo_s[ol] + spatial[off] + freq[off];
      }
    }
}

extern "C" void kernel_launch(void* const* d_in, const int* in_sizes, int n_in,
                              void* d_out, int out_size, void* d_ws, size_t ws_size,
                              hipStream_t stream) {
  const float* spatial = (const float*)d_in[0];
  const float* freq    = (const float*)d_in[1];
  const float* wq = (const float*)d_in[2];
  const float* bq = (const float*)d_in[3];
  const float* wk = (const float*)d_in[4];
  const float* bk = (const float*)d_in[5];
  const float* wv = (const float*)d_in[6];
  const float* bv = (const float*)d_in[7];
  const float* wo = (const float*)d_in[8];
  const float* bo = (const float*)d_in[9];
  float* out = (float*)d_out;

  // workspace layout (bf16 elements)
  const size_t SZ = (size_t)2 * B_ * N_ * C_;   // 4M elems = 8 MB
  bf16* xb    = (bf16*)d_ws;                    // [z][p][c]
  bf16* qhf   = xb + SZ;                        // [z][h][n][d]
  bf16* khf   = qhf + SZ;                       // [z][h][n][d]
  bf16* vhf   = khf + SZ;                       // [z][h] frag-blocked
  bf16* attoT = vhf + SZ;                       // [z][p][c]
  bf16* wb    = attoT + SZ;                     // [768][256]
  bf16* wob   = wb + 768 * 256;                 // [256][256]

  convert_w_kernel<<<dim3(1024), 256, 0, stream>>>(wq, wk, wv, wo, wb, wob);
  convert_x_kernel<<<dim3(N_ / 64, C_ / 64, 2 * B_), 256, 0, stream>>>(
      spatial, freq, xb);
  qkv_gemm_kernel<<<dim3(N_ / 128, 768 / 128, 2 * B_), 256, 0, stream>>>(
      wb, xb, bq, bk, bv, qhf, khf, vhf);
  attn_kernel<<<dim3(N_ / 128, NH_, 2 * B_), 256, 0, stream>>>(
      qhf, khf, vhf, attoT);
  out_proj_kernel<<<dim3(N_ / 128, C_ / 64, B_), 256, 0, stream>>>(
      wob, attoT, spatial, freq, bo, out);
}